// Round 13
// baseline (41.847 us; speedup 1.0000x reference)
//
#include <hip/hip_runtime.h>

// HierarchicalMultinomialRegression: channel-parallel fused kernel, round 13.
// = round 11 (35.9us, best) + single-exposure eps gather.
//
// r11's fold had 3 divergent branch bodies, each load->waitcnt->compute ->
// up to 3 serialized L3 round-trips (~600cy each) per wave. Here ALL eps
// loads (3 owned rows = 21 dwords, clamped s_ld=min(s,19), + e0 + last_e)
// issue unconditionally in one 23-deep MLP burst BEFORE the GEMV (latency
// hides under ~100 GEMV instrs); the fold becomes branchless via cndmask:
//   q = (active? r8 : 1)*q + (active? nz : 0)
// which reproduces the guarded fold exactly (inactive steps leave q
// untouched; residual scale rho^{(t-p-1)&7} logic unchanged from r11).
// r12's readlane experiment reverted (regressed 2.3us: 49 serialized
// v_readlane + extra global loads beat 49 broadcast ds_read_b32).
// No launch_bounds min-waves cap (spill lessons r2/r6/r7).
//
// Math (verified r11): u_t[j] = rho_j^t sd_j e0[j] + sum_s rho_j^{t-s} nz_s[j],
// nz_s[j] = sum_k eps_s[k] M[k][j]; lane p owns steps {p+1,p+9,p+17};
// forward fold with rho^8 gaps; 21-shfl_xor butterfly; static select.
//
// Inputs: 0:X(N,64) 1:beta(64,7) 2:raw_rho(7,7) 3:raw_chol(7,7,7)
//         4:eps(B,7,20,7) 5:batter_ids 6:league_ids 7:season_ids
// Output: logits (N,8) then eps_sample (N,7), concat flat, f32.

#define NF 64
#define LDIM 7
#define TDIM 20
#define KM1 7
#define BLOCK 256
#define RPB (BLOCK / 8)   // rows per block = 32
#define BPAD 68           // betaT row stride (floats)

__device__ __forceinline__ float rfl(float x) {
    return __int_as_float(__builtin_amdgcn_readfirstlane(__float_as_int(x)));
}

__global__ __launch_bounds__(BLOCK) void hmr_kernel(
    const float* __restrict__ X,
    const float* __restrict__ beta,
    const float* __restrict__ raw_rho,
    const float* __restrict__ raw_chol,
    const float* __restrict__ eps,
    const int* __restrict__ batter_ids,
    const int* __restrict__ league_ids,
    const int* __restrict__ season_ids,
    float* __restrict__ out,
    int n_total)
{
    __shared__ __align__(16) float s_betaT[8][BPAD];  // betaT[k][j] = beta[j][k]
    __shared__ float s_rho[LDIM * 8];    // rho[l][k]
    __shared__ float s_sd[LDIM * 8];     // sd[l][k]
    __shared__ float s_M[64];            // M[k][j] stride 8, padded zero

    const int tid = threadIdx.x;

    for (int i = tid; i < NF * KM1; i += BLOCK) {
        const int j = i / KM1, k = i - j * KM1;
        s_betaT[k][j] = beta[i];
    }
    if (tid < 64) {
        const int a = tid >> 3, c = tid & 7;
        float m = 0.f;
        if (a < KM1 && c < KM1) {
            #pragma unroll
            for (int i2 = 0; i2 < LDIM; ++i2)
                m += raw_chol[a * 49 + i2 * 7 + c];   // M[k=a][j=c]
        }
        s_M[tid] = m;
        if (a < LDIM) {
            float r = 0.f, sdv = 0.f;
            if (c < KM1) {
                r = tanhf(raw_rho[a * KM1 + c]);
                sdv = (1.0f / sqrtf(1.0f - r * r)) * raw_chol[c * 49 + a * 7 + a];
            }
            s_rho[a * 8 + c] = r;
            s_sd[a * 8 + c] = sdv;
        }
    }
    __syncthreads();

    const int r = tid >> 3;          // row within block
    const int p = tid & 7;           // lane-in-group: channel & step owner
    const int k_ld = (p < 6) ? p : 6;
    int n = blockIdx.x * RPB + r;
    const bool valid = (n < n_total);
    if (!valid) n = n_total - 1;

    const int b = batter_ids[n];
    const int l = league_ids[n];
    const int t = season_ids[n];

    const float* __restrict__ erow = eps + ((long)b * LDIM + l) * (TDIM * KM1);

    // ---- issue ALL eps loads unconditionally (clamped, in-bounds): one
    //      23-deep MLP burst whose latency hides under the GEMV below ----
    float ev[3][KM1];
    #pragma unroll
    for (int i = 0; i < 3; ++i) {
        const int s = p + 1 + 8 * i;
        const int s_ld = (s < TDIM) ? s : (TDIM - 1);
        #pragma unroll
        for (int k = 0; k < KM1; ++k) ev[i][k] = erow[s_ld * KM1 + k];
    }
    const float e0 = erow[k_ld];
    const float last_e = erow[t * KM1 + k_ld];

    // ---- fixed effects: acc = sum_j X[n,j] * beta[j, p] ----
    float acc = 0.f;
    {
        const float4* __restrict__ xrow =
            reinterpret_cast<const float4*>(X + (long)n * NF);
        const float4* __restrict__ brow =
            reinterpret_cast<const float4*>(&s_betaT[k_ld][0]);
        #pragma unroll 4
        for (int j4 = 0; j4 < NF / 4; ++j4) {
            const float4 x = xrow[j4];
            const float4 bb = brow[j4];
            acc = fmaf(x.x, bb.x, fmaf(x.y, bb.y,
                  fmaf(x.z, bb.z, fmaf(x.w, bb.w, acc))));
        }
    }

    // ---- hoist wave-uniform M into SGPRs (broadcast LDS reads) ----
    float mm[KM1 * KM1];
    #pragma unroll
    for (int k = 0; k < KM1; ++k)
        #pragma unroll
        for (int j = 0; j < KM1; ++j)
            mm[k * KM1 + j] = rfl(s_M[k * 8 + j]);

    // ---- per-group rho vector + rho^8 ----
    float rho_all[KM1], r8[KM1];
    #pragma unroll
    for (int j = 0; j < KM1; ++j) {
        rho_all[j] = s_rho[l * 8 + j];
        const float r2 = rho_all[j] * rho_all[j];
        const float r4 = r2 * r2;
        r8[j] = r4 * r4;
    }

    // ---- branchless forward fold over owned steps s = p+1+8i ----
    float q[KM1];
    #pragma unroll
    for (int j = 0; j < KM1; ++j) q[j] = 0.f;

    #pragma unroll
    for (int i = 0; i < 3; ++i) {
        const int s = p + 1 + 8 * i;
        const bool act = (s <= t);
        #pragma unroll
        for (int j = 0; j < KM1; ++j) {
            float nz = 0.f;
            #pragma unroll
            for (int k = 0; k < KM1; ++k)
                nz = fmaf(ev[i][k], mm[k * KM1 + j], nz);  // SGPR operand
            q[j] = fmaf(act ? r8[j] : 1.f, q[j], act ? nz : 0.f);
        }
    }

    // ---- scale by rho_j^((t-p-1)&7)  (q==0 when t<p+1, so &7 is safe) ----
    {
        const int m = (t - p - 1) & 7;
        float bs[KM1];
        #pragma unroll
        for (int j = 0; j < KM1; ++j) bs[j] = rho_all[j];
        #pragma unroll
        for (int bit = 0; bit < 3; ++bit) {
            const bool on = ((m >> bit) & 1) != 0;
            #pragma unroll
            for (int j = 0; j < KM1; ++j) {
                q[j] *= on ? bs[j] : 1.f;
                bs[j] *= bs[j];
            }
        }
    }

    // ---- butterfly-sum q over the 8-lane group ----
    #pragma unroll
    for (int j = 0; j < KM1; ++j) {
        q[j] += __shfl_xor(q[j], 1, 8);
        q[j] += __shfl_xor(q[j], 2, 8);
        q[j] += __shfl_xor(q[j], 4, 8);
    }
    // select own channel (static indices -> cndmask chain)
    float nzt = q[0];
    #pragma unroll
    for (int j = 1; j < KM1; ++j) nzt = (p == j) ? q[j] : nzt;

    // ---- e0 term: rho_own^t * sd * e0 ----
    const float sd = s_sd[l * 8 + k_ld];
    float rho_own = rho_all[0];
    #pragma unroll
    for (int j = 1; j < KM1; ++j) rho_own = (k_ld == j) ? rho_all[j] : rho_own;
    float pwt = 1.f;
    {
        float bo = rho_own;
        #pragma unroll
        for (int bit = 0; bit < 5; ++bit) {
            pwt *= (((t >> bit) & 1) != 0) ? bo : 1.f;
            bo *= bo;
        }
    }
    const float u = fmaf(pwt * sd, e0, nzt);

    // ---- coalesced writes, no staging ----
    if (valid) {
        const int col = (p == 7) ? 0 : p + 1;
        out[(long)n * 8 + col] = (p == 7) ? 0.f : (acc + u);
        if (p < KM1)
            out[(long)n_total * 8 + (long)n * KM1 + p] = last_e;
    }
}

extern "C" void kernel_launch(void* const* d_in, const int* in_sizes, int n_in,
                              void* d_out, int out_size, void* d_ws, size_t ws_size,
                              hipStream_t stream)
{
    const float* X        = (const float*)d_in[0];
    const float* beta     = (const float*)d_in[1];
    const float* raw_rho  = (const float*)d_in[2];
    const float* raw_chol = (const float*)d_in[3];
    const float* eps      = (const float*)d_in[4];
    const int* batter_ids = (const int*)d_in[5];
    const int* league_ids = (const int*)d_in[6];
    const int* season_ids = (const int*)d_in[7];
    float* out = (float*)d_out;

    const int n_total = in_sizes[5];  // N = 200000
    const int grid = (n_total + RPB - 1) / RPB;

    hmr_kernel<<<grid, BLOCK, 0, stream>>>(X, beta, raw_rho, raw_chol, eps,
                                           batter_ids, league_ids, season_ids,
                                           out, n_total);
}

// Round 14
// 38.438 us; speedup vs baseline: 1.0887x; 1.0887x over previous
//
#include <hip/hip_runtime.h>

// HierarchicalMultinomialRegression: channel-parallel fused kernel, round 14.
// = round 11 (35.9us, best) + PREDICATED early eps loads (latency overlap
// without r13's traffic confound).
//
// r13 post-mortem: clamped unconditional loads made every lane fetch 3 eps
// rows (vs ~1.3 active) -> ~2.3x eps line touches -> 41.8us. Here the loads
// keep r11's exec-mask predication (if s<=t: inactive lanes issue NOTHING)
// but are hoisted BEFORE the GEMV as three independent guarded bursts into
// zero-init ev[3][7] (statically indexed); first use is ~100 instrs later,
// so the L3 round-trip hides under the GEMV. Fold is r13's branchless
// cndmask form (inactive ev values never contribute).
// If this lands ~36us, latency was already TLP-hidden and r11/r14 is the
// random-gather L2/L3 bandwidth roofline.
//
// Math (verified r11): u_t[j] = rho_j^t sd_j e0[j] + sum_s rho_j^{t-s} nz_s[j],
// nz_s[j] = sum_k eps_s[k] M[k][j]; lane p owns steps {p+1,p+9,p+17};
// forward fold with rho^8 gaps; residual scale rho^{(t-p-1)&7};
// 21-shfl_xor butterfly; static cndmask select.
// No launch_bounds min-waves cap (spill lessons r2/r6/r7).
//
// Inputs: 0:X(N,64) 1:beta(64,7) 2:raw_rho(7,7) 3:raw_chol(7,7,7)
//         4:eps(B,7,20,7) 5:batter_ids 6:league_ids 7:season_ids
// Output: logits (N,8) then eps_sample (N,7), concat flat, f32.

#define NF 64
#define LDIM 7
#define TDIM 20
#define KM1 7
#define BLOCK 256
#define RPB (BLOCK / 8)   // rows per block = 32
#define BPAD 68           // betaT row stride (floats)

__device__ __forceinline__ float rfl(float x) {
    return __int_as_float(__builtin_amdgcn_readfirstlane(__float_as_int(x)));
}

__global__ __launch_bounds__(BLOCK) void hmr_kernel(
    const float* __restrict__ X,
    const float* __restrict__ beta,
    const float* __restrict__ raw_rho,
    const float* __restrict__ raw_chol,
    const float* __restrict__ eps,
    const int* __restrict__ batter_ids,
    const int* __restrict__ league_ids,
    const int* __restrict__ season_ids,
    float* __restrict__ out,
    int n_total)
{
    __shared__ __align__(16) float s_betaT[8][BPAD];  // betaT[k][j] = beta[j][k]
    __shared__ float s_rho[LDIM * 8];    // rho[l][k]
    __shared__ float s_sd[LDIM * 8];     // sd[l][k]
    __shared__ float s_M[64];            // M[k][j] stride 8, padded zero

    const int tid = threadIdx.x;

    for (int i = tid; i < NF * KM1; i += BLOCK) {
        const int j = i / KM1, k = i - j * KM1;
        s_betaT[k][j] = beta[i];
    }
    if (tid < 64) {
        const int a = tid >> 3, c = tid & 7;
        float m = 0.f;
        if (a < KM1 && c < KM1) {
            #pragma unroll
            for (int i2 = 0; i2 < LDIM; ++i2)
                m += raw_chol[a * 49 + i2 * 7 + c];   // M[k=a][j=c]
        }
        s_M[tid] = m;
        if (a < LDIM) {
            float r = 0.f, sdv = 0.f;
            if (c < KM1) {
                r = tanhf(raw_rho[a * KM1 + c]);
                sdv = (1.0f / sqrtf(1.0f - r * r)) * raw_chol[c * 49 + a * 7 + a];
            }
            s_rho[a * 8 + c] = r;
            s_sd[a * 8 + c] = sdv;
        }
    }
    __syncthreads();

    const int r = tid >> 3;          // row within block
    const int p = tid & 7;           // lane-in-group: channel & step owner
    const int k_ld = (p < 6) ? p : 6;
    int n = blockIdx.x * RPB + r;
    const bool valid = (n < n_total);
    if (!valid) n = n_total - 1;

    const int b = batter_ids[n];
    const int l = league_ids[n];
    const int t = season_ids[n];

    const float* __restrict__ erow = eps + ((long)b * LDIM + l) * (TDIM * KM1);

    // ---- PREDICATED early eps loads: same traffic as r11 (exec-masked),
    //      issued as one burst before the GEMV so latency hides under it ----
    float ev[3][KM1];
    #pragma unroll
    for (int i = 0; i < 3; ++i)
        #pragma unroll
        for (int k = 0; k < KM1; ++k) ev[i][k] = 0.f;

    #pragma unroll
    for (int i = 0; i < 3; ++i) {
        const int s = p + 1 + 8 * i;
        if (s <= t) {                      // exec-masked: no load if inactive
            #pragma unroll
            for (int k = 0; k < KM1; ++k) ev[i][k] = erow[s * KM1 + k];
        }
    }
    const float e0 = erow[k_ld];
    const float last_e = erow[t * KM1 + k_ld];

    // ---- fixed effects: acc = sum_j X[n,j] * beta[j, p] ----
    float acc = 0.f;
    {
        const float4* __restrict__ xrow =
            reinterpret_cast<const float4*>(X + (long)n * NF);
        const float4* __restrict__ brow =
            reinterpret_cast<const float4*>(&s_betaT[k_ld][0]);
        #pragma unroll 4
        for (int j4 = 0; j4 < NF / 4; ++j4) {
            const float4 x = xrow[j4];
            const float4 bb = brow[j4];
            acc = fmaf(x.x, bb.x, fmaf(x.y, bb.y,
                  fmaf(x.z, bb.z, fmaf(x.w, bb.w, acc))));
        }
    }

    // ---- hoist wave-uniform M into SGPRs (broadcast LDS reads) ----
    float mm[KM1 * KM1];
    #pragma unroll
    for (int k = 0; k < KM1; ++k)
        #pragma unroll
        for (int j = 0; j < KM1; ++j)
            mm[k * KM1 + j] = rfl(s_M[k * 8 + j]);

    // ---- per-group rho vector + rho^8 ----
    float rho_all[KM1], r8[KM1];
    #pragma unroll
    for (int j = 0; j < KM1; ++j) {
        rho_all[j] = s_rho[l * 8 + j];
        const float r2 = rho_all[j] * rho_all[j];
        const float r4 = r2 * r2;
        r8[j] = r4 * r4;
    }

    // ---- branchless forward fold over owned steps s = p+1+8i ----
    float q[KM1];
    #pragma unroll
    for (int j = 0; j < KM1; ++j) q[j] = 0.f;

    #pragma unroll
    for (int i = 0; i < 3; ++i) {
        const int s = p + 1 + 8 * i;
        const bool act = (s <= t);
        #pragma unroll
        for (int j = 0; j < KM1; ++j) {
            float nz = 0.f;
            #pragma unroll
            for (int k = 0; k < KM1; ++k)
                nz = fmaf(ev[i][k], mm[k * KM1 + j], nz);  // SGPR operand
            q[j] = fmaf(act ? r8[j] : 1.f, q[j], act ? nz : 0.f);
        }
    }

    // ---- scale by rho_j^((t-p-1)&7)  (q==0 when t<p+1, so &7 is safe) ----
    {
        const int m = (t - p - 1) & 7;
        float bs[KM1];
        #pragma unroll
        for (int j = 0; j < KM1; ++j) bs[j] = rho_all[j];
        #pragma unroll
        for (int bit = 0; bit < 3; ++bit) {
            const bool on = ((m >> bit) & 1) != 0;
            #pragma unroll
            for (int j = 0; j < KM1; ++j) {
                q[j] *= on ? bs[j] : 1.f;
                bs[j] *= bs[j];
            }
        }
    }

    // ---- butterfly-sum q over the 8-lane group ----
    #pragma unroll
    for (int j = 0; j < KM1; ++j) {
        q[j] += __shfl_xor(q[j], 1, 8);
        q[j] += __shfl_xor(q[j], 2, 8);
        q[j] += __shfl_xor(q[j], 4, 8);
    }
    // select own channel (static indices -> cndmask chain)
    float nzt = q[0];
    #pragma unroll
    for (int j = 1; j < KM1; ++j) nzt = (p == j) ? q[j] : nzt;

    // ---- e0 term: rho_own^t * sd * e0 ----
    const float sd = s_sd[l * 8 + k_ld];
    float rho_own = rho_all[0];
    #pragma unroll
    for (int j = 1; j < KM1; ++j) rho_own = (k_ld == j) ? rho_all[j] : rho_own;
    float pwt = 1.f;
    {
        float bo = rho_own;
        #pragma unroll
        for (int bit = 0; bit < 5; ++bit) {
            pwt *= (((t >> bit) & 1) != 0) ? bo : 1.f;
            bo *= bo;
        }
    }
    const float u = fmaf(pwt * sd, e0, nzt);

    // ---- coalesced writes, no staging ----
    if (valid) {
        const int col = (p == 7) ? 0 : p + 1;
        out[(long)n * 8 + col] = (p == 7) ? 0.f : (acc + u);
        if (p < KM1)
            out[(long)n_total * 8 + (long)n * KM1 + p] = last_e;
    }
}

extern "C" void kernel_launch(void* const* d_in, const int* in_sizes, int n_in,
                              void* d_out, int out_size, void* d_ws, size_t ws_size,
                              hipStream_t stream)
{
    const float* X        = (const float*)d_in[0];
    const float* beta     = (const float*)d_in[1];
    const float* raw_rho  = (const float*)d_in[2];
    const float* raw_chol = (const float*)d_in[3];
    const float* eps      = (const float*)d_in[4];
    const int* batter_ids = (const int*)d_in[5];
    const int* league_ids = (const int*)d_in[6];
    const int* season_ids = (const int*)d_in[7];
    float* out = (float*)d_out;

    const int n_total = in_sizes[5];  // N = 200000
    const int grid = (n_total + RPB - 1) / RPB;

    hmr_kernel<<<grid, BLOCK, 0, stream>>>(X, beta, raw_rho, raw_chol, eps,
                                           batter_ids, league_ids, season_ids,
                                           out, n_total);
}